// Round 20
// baseline (100.384 us; speedup 1.0000x reference)
//
#include <hip/hip_runtime.h>
#include <math.h>

#define T_DIM 2048
#define B_DIM 96
#define C_DIM 128
#define L_DIM 128
#define LOG2E 1.4426950408889634f
#define LN2 0.69314718055994531f
#define SMOOTH 0.1f
#define SENT (-(1 << 30))
#define SENTF (-1073741824.0f)
#define NPH 32

// ws layout (floats)
#define AOFF 0
#define BOFF 24672
#define KLA  49344
#define KLB  49440
#define LOSS 49536

__device__ __forceinline__ float dpp_shr1_f(float x) {
  return __int_as_float(__builtin_amdgcn_update_dpp(
      0, __float_as_int(x), 0x138 /*WAVE_SR1*/, 0xF, 0xF, true));
}
__device__ __forceinline__ float dpp_shl1_f(float x) {
  return __int_as_float(__builtin_amdgcn_update_dpp(
      0, __float_as_int(x), 0x130 /*WAVE_SL1*/, 0xF, 0xF, true));
}

// Window exchange (R18/R19-proven).
#define AEXCH() do {                                                         \
  const float m = fmaxf(fmaxf(fmaxf(r0, r1), fmaxf(r2, r3)), r4);            \
  const int sh2 = (m > 0.0f) ? (177 - ((__float_as_int(m) >> 23) & 0xFF)) : 0;\
  r0 = ldexpf(r0, sh2); r1 = ldexpf(r1, sh2); r2 = ldexpf(r2, sh2);          \
  r3 = ldexpf(r3, sh2); r4 = ldexpf(r4, sh2);                                \
  E -= sh2;                                                                  \
  float Esf = dpp_shr1_f((float)E);                                          \
  Esf = (tid == 0) ? SENTF : Esf;                                            \
  const int Es = (int)Esf;                                                   \
  const bool live = (Es != SENT);                                            \
  if (E == SENT && live) E = Es;                                             \
  int sh = (Es - E) - 60; sh = (sh > 0) ? sh : 0; sh = (sh > 252) ? 252 : sh;\
  r0 = ldexpf(r0, -sh); r1 = ldexpf(r1, -sh); r2 = ldexpf(r2, -sh);          \
  r3 = ldexpf(r3, -sh); r4 = ldexpf(r4, -sh);                                \
  E += sh;                                                                   \
  const int diff = Es - E;                                                   \
  int dc = (diff < -126) ? -126 : diff;                                      \
  float sc = __int_as_float((127 + dc) << 23);                               \
  sc = (diff < -126) ? 0.0f : sc;                                            \
  scale = live ? sc : 0.0f;                                                  \
} while (0)

#define BEXCH() do {                                                         \
  const float m = fmaxf(fmaxf(fmaxf(r0, r1), fmaxf(r2, r3)), r4);            \
  const int sh2 = (m > 0.0f) ? (177 - ((__float_as_int(m) >> 23) & 0xFF)) : 0;\
  r0 = ldexpf(r0, sh2); r1 = ldexpf(r1, sh2); r2 = ldexpf(r2, sh2);          \
  r3 = ldexpf(r3, sh2); r4 = ldexpf(r4, sh2);                                \
  E -= sh2;                                                                  \
  float Esf = dpp_shl1_f((float)E);                                          \
  Esf = (tid == 63) ? SENTF : Esf;                                           \
  const int Es = (int)Esf;                                                   \
  const bool live = (Es != SENT);                                            \
  if (E == SENT && live) E = Es;                                             \
  int sh = (Es - E) - 60; sh = (sh > 0) ? sh : 0; sh = (sh > 252) ? 252 : sh;\
  r0 = ldexpf(r0, -sh); r1 = ldexpf(r1, -sh); r2 = ldexpf(r2, -sh);          \
  r3 = ldexpf(r3, -sh); r4 = ldexpf(r4, -sh);                                \
  E += sh;                                                                   \
  const int diff = Es - E;                                                   \
  int dc = (diff < -126) ? -126 : diff;                                      \
  float sc = __int_as_float((127 + dc) << 23);                               \
  sc = (diff < -126) ? 0.0f : sc;                                            \
  scale = live ? sc : 0.0f;                                                  \
} while (0)

// ---- 2-step COMPOSED alpha macro (rows 2j = P first, 2j+1 = Q second) ----
// alpha''[s] = Q[s]*(c0 a[s] + c1 a[s-1] + c2 a[s-2] + c3 a[s-3] + c4 a[s-4])
#define AMACRO(j_) do {                                                      \
  const float* rP = pc + (2 * (j_)) * C_DIM;                                 \
  const float* rQ = pc + (2 * (j_) + 1) * C_DIM;                             \
  const float PA = rP[tgA], PB = rP[tgB], PP = rP[tgP], PK = rP[0];          \
  const float QA = rQ[tgA], QB = rQ[tgB], QK = rQ[0];                        \
  const float d1 = dpp_shr1_f(r1) * scale;                                   \
  const float d2 = dpp_shr1_f(r2) * scale;                                   \
  const float d3 = dpp_shr1_f(r3) * scale;                                   \
  const float u01 = PK + PP;                                                 \
  const float t1  = PP * skBp;                                               \
  const float c1A = PA + PK;                                                 \
  const float c2A = __builtin_fmaf(skA, PP, __builtin_fmaf(PA, skA, PK));    \
  const float c3A = skA * PP;                                                \
  const float c4A = skA * t1;                                                \
  const float c1K2 = PK + PA;                                                \
  const float w2  = PA * skA;                                                \
  const float c1B = PB + PK;                                                 \
  const float c2B = __builtin_fmaf(skB, PA, __builtin_fmaf(PB, skB, PK));    \
  const float c3B = skB * PA;                                                \
  const float c4B = skA * c3B;                                               \
  const float c1K4 = PK + PB;                                                \
  const float w4  = PB * skB;                                                \
  const float n0 = QK * __builtin_fmaf(PK, r0, __builtin_fmaf(u01, d3,      \
                      __builtin_fmaf(PP, d2, t1 * d1)));                     \
  const float n1 = QA * __builtin_fmaf(PA, r1, __builtin_fmaf(c1A, r0,      \
                      __builtin_fmaf(c2A, d3, __builtin_fmaf(c3A, d2,       \
                      c4A * d1))));                                          \
  const float n2 = QK * __builtin_fmaf(PK, r2, __builtin_fmaf(c1K2, r1,     \
                      __builtin_fmaf(PA, r0, w2 * d3)));                     \
  const float n3 = QB * __builtin_fmaf(PB, r3, __builtin_fmaf(c1B, r2,      \
                      __builtin_fmaf(c2B, r1, __builtin_fmaf(c3B, r0,       \
                      c4B * d3))));                                          \
  const float n4 = QK * __builtin_fmaf(PK, r4, __builtin_fmaf(c1K4, r3,     \
                      __builtin_fmaf(PB, r2, w4 * r1)));                     \
  r0 = n0; r1 = n1; r2 = n2; r3 = n3; r4 = n4;                               \
  if ((j_) & 1) { AEXCH(); }                                                 \
} while (0)

// ---- 2-step COMPOSED beta macro (rows 2j = P = higher t, 2j+1 = Q) ----
#define BMACRO(j_) do {                                                      \
  const float* rP = pc + (2 * (j_)) * C_DIM;                                 \
  const float* rQ = pc + (2 * (j_) + 1) * C_DIM;                             \
  const float PA = rP[tgA], PB = rP[tgB], PN = rP[tgAn], PBn = rP[tgBn];     \
  const float PK = rP[0];                                                    \
  const float QA = rQ[tgA], QB = rQ[tgB], QN = rQ[tgAn], QK = rQ[0];         \
  const float d1 = dpp_shl1_f(r1) * scale;                                   \
  const float d2 = dpp_shl1_f(r2) * scale;                                   \
  const float d3 = dpp_shl1_f(r3) * scale;                                   \
  const float m0 = PK * r0, m1 = PA * r1, m2 = PK * r2;                      \
  const float m3 = PB * r3, m4 = PK * r4;                                    \
  const float m5 = PN * d1, m6 = PK * d2, m7 = PBn * d3;                     \
  const float u1 = QK + QA;                                                  \
  const float vB = QA * skB;                                                 \
  const float e2_1 = __builtin_fmaf(skB, QB, __builtin_fmaf(QA, skB, QK));   \
  const float e3_1 = skB * QB;                                               \
  const float e4_1 = skAn * e3_1;                                            \
  const float u2 = QK + QB;                                                  \
  const float v2 = QB * skAn;                                                \
  const float e2_3 = __builtin_fmaf(skAn, QN, __builtin_fmaf(QB, skAn, QK)); \
  const float e3_3 = skAn * QN;                                              \
  const float e4_3 = skBn * e3_3;                                            \
  const float u4 = QK + QN;                                                  \
  const float v4 = QN * skBn;                                                \
  const float n0 = __builtin_fmaf(QK, m0, __builtin_fmaf(u1, m1,             \
                      __builtin_fmaf(QA, m2, vB * m3)));                     \
  const float n1 = __builtin_fmaf(QA, m1, __builtin_fmaf(u1, m2,             \
                      __builtin_fmaf(e2_1, m3, __builtin_fmaf(e3_1, m4,      \
                      e4_1 * m5))));                                         \
  const float n2 = __builtin_fmaf(QK, m2, __builtin_fmaf(u2, m3,             \
                      __builtin_fmaf(QB, m4, v2 * m5)));                     \
  const float n3 = __builtin_fmaf(QB, m3, __builtin_fmaf(u2, m4,             \
                      __builtin_fmaf(e2_3, m5, __builtin_fmaf(e3_3, m6,      \
                      e4_3 * m7))));                                         \
  const float n4 = __builtin_fmaf(QK, m4, __builtin_fmaf(u4, m5,             \
                      __builtin_fmaf(QN, m6, v4 * m7)));                     \
  r0 = n0; r1 = n1; r2 = n2; r3 = n3; r4 = n4;                               \
  if ((j_) & 1) { BEXCH(); }                                                 \
} while (0)

// Single-step math (R18-proven) — used only in guarded tail phases.
#define AMATH(par_, j_) do {                                                 \
  const float pAv = sA[par_][j_], pBv = sB[par_][j_], pKv = sK[par_][j_];    \
  const float r3s = dpp_shr1_f(r3);                                          \
  const float d3  = r3s * scale;                                             \
  const float n0 = (r0 + d3) * pKv;                                          \
  const float n1 = __builtin_fmaf(skA, d3, r0 + r1) * pAv;                   \
  const float n2 = (r2 + r1) * pKv;                                          \
  const float n3 = __builtin_fmaf(skB, r1, r3 + r2) * pBv;                   \
  const float n4 = (r4 + r3) * pKv;                                          \
  r0 = n0; r1 = n1; r2 = n2; r3 = n3; r4 = n4;                               \
} while (0)

#define BMATH(par_, j_) do {                                                 \
  const float pAv = sA[par_][j_], pBv = sB[par_][j_], pKv = sK[par_][j_];    \
  const float pNv = sN[par_][j_];                                            \
  const float r1s = dpp_shl1_f(r1);                                          \
  const float d5  = r1s * scale;                                             \
  const float g0 = r0 * pKv, g1 = r1 * pAv, g2 = r2 * pKv;                   \
  const float g3 = r3 * pBv, g4 = r4 * pKv, g5 = d5 * pNv;                   \
  const float n0 = g0 + g1;                                                  \
  const float n1 = __builtin_fmaf(skB, g3, g1 + g2);                         \
  const float n2 = g2 + g3;                                                  \
  const float n3 = __builtin_fmaf(skAn, g5, g3 + g4);                        \
  const float n4 = g4 + g5;                                                  \
  r0 = n0; r1 = n1; r2 = n2; r3 = n3; r4 = n4;                               \
} while (0)

#define ASTEP_G(k_, cond_) do {                                              \
  const int kn_ = (k_) + 4;                                                  \
  {                                                                          \
    const float* nr = (kn_ < 32) ? (pc + kn_ * C_DIM)                        \
                                 : (pn + (kn_ - 32) * C_DIM);                \
    sA[(kn_ >> 2) & 1][kn_ & 3] = nr[tgA];                                   \
    sB[(kn_ >> 2) & 1][kn_ & 3] = nr[tgB];                                   \
    sK[(kn_ >> 2) & 1][kn_ & 3] = nr[0];                                     \
  }                                                                          \
  if (cond_) {                                                               \
    AMATH(((k_) >> 2) & 1, (k_) & 3);                                        \
    if (((k_) & 3) == 3) { AEXCH(); }                                        \
  }                                                                          \
} while (0)

#define BSTEP_G(k_, cond_) do {                                              \
  const int kn_ = (k_) + 4;                                                  \
  {                                                                          \
    const float* nr = (kn_ < 32) ? (pc + kn_ * C_DIM)                        \
                                 : (pn + (kn_ - 32) * C_DIM);                \
    sA[(kn_ >> 2) & 1][kn_ & 3] = nr[tgA];                                   \
    sB[(kn_ >> 2) & 1][kn_ & 3] = nr[tgB];                                   \
    sK[(kn_ >> 2) & 1][kn_ & 3] = nr[0];                                     \
    sN[(kn_ >> 2) & 1][kn_ & 3] = nr[tgAn];                                  \
  }                                                                          \
  if (cond_) {                                                               \
    BMATH(((k_) >> 2) & 1, (k_) & 3);                                        \
    if (((k_) & 3) == 3) { BEXCH(); }                                        \
  }                                                                          \
} while (0)

// Blocks 0..95: ALPHA (t=0..1023). Blocks 96..191: BETA (rows 2047..1024).
// Fast phases use 16 composed macro-steps (2 rows each); tails use proven
// guarded singles with set priming.
__global__ __launch_bounds__(256) void ctc_fused_kernel(
    const float* __restrict__ lp, const int* __restrict__ targets,
    const int* __restrict__ in_len, const int* __restrict__ tg_len,
    float* __restrict__ ws)
{
  const int tid = threadIdx.x;
  const int bid = blockIdx.x;
  const int isBeta = (bid >= B_DIM);
  const int b = isBeta ? bid - B_DIM : bid;
  const size_t RSTR = (size_t)B_DIM * C_DIM;
  const int Tb = in_len[b];
  const float* base = lp + (size_t)b * C_DIM;

  __shared__ float rows[3][32][C_DIM];
  __shared__ float klred[3];

  float klacc = 0.f;

  if (!isBeta) {
    // ================= ALPHA half =================
    const int TbA = (Tb < 1024) ? Tb : 1024;
    int tgA = 0, tgB = 0, tgP = 0;
    float skA = 0.f, skB = 0.f, skBp = 0.f;
    float r0 = 0.f, r1 = 0.f, r2 = 0.f, r3 = 0.f, r4 = 0.f;
    int E = SENT;
    float scale = 0.f;
    float sA[2][4], sB[2][4], sK[2][4];

    if (tid < 64) {
      const int l = tid;
      tgA = targets[b * L_DIM + 2 * l];
      tgB = targets[b * L_DIM + 2 * l + 1];
      tgP = (l > 0) ? targets[b * L_DIM + 2 * l - 1] : 0;   // prev lane's tgB
      skA = (l > 0 && tgA != tgP) ? 1.f : 0.f;
      skB = (tgB != tgA) ? 1.f : 0.f;
      skBp = (l > 0 && tgP != targets[b * L_DIM + 2 * l - 2]) ? 1.f : 0.f;
      if (l == 0) {
        r0 = __builtin_amdgcn_exp2f(base[0]   * LOG2E);
        r1 = __builtin_amdgcn_exp2f(base[tgA] * LOG2E);
        E = 0;
      }
    } else {
      const int ptid = tid - 64;
      #pragma unroll
      for (int i = 0; i < 11; ++i) {
        const int task = i * 192 + ptid;
        if (task < 2048) {
          const int row = task >> 5;
          const int c4  = task & 31;
          const int t   = 1 + row;
          const float4 v = *(const float4*)(base + (size_t)t * RSTR + c4 * 4);
          float4 w;
          w.x = __builtin_amdgcn_exp2f(v.x * LOG2E);
          w.y = __builtin_amdgcn_exp2f(v.y * LOG2E);
          w.z = __builtin_amdgcn_exp2f(v.z * LOG2E);
          w.w = __builtin_amdgcn_exp2f(v.w * LOG2E);
          *(float4*)&rows[row >> 5][row & 31][c4 * 4] = w;
          if (t < Tb) {
            float s = v.x + v.y + v.z + v.w;
            if (c4 == 0) s -= v.x;
            klacc += s;
          }
        }
      }
      if (ptid < 32 && 0 < Tb) {
        const float4 v = *(const float4*)(base + ptid * 4);
        float s = v.x + v.y + v.z + v.w;
        if (ptid == 0) s -= v.x;
        klacc += s;
      }
    }
    __syncthreads();

    if (tid < 64) { AEXCH(); }                    // initial frame exchange
    float* pc = &rows[0][0][0];
    float* pn = &rows[1][0][0];
    float* pf = &rows[2][0][0];

    for (int p = 0; p < NPH; ++p) {
      if (tid < 64) {
        if (32 * p + 33 <= TbA) {
          // FAST: 16 composed macros (32 steps)
          #pragma unroll
          for (int j = 0; j < 16; ++j) { AMACRO(j); }
        } else {
          // tail: prime sets, then guarded singles
          #pragma unroll
          for (int j = 0; j < 4; ++j) {
            sA[0][j] = pc[j * C_DIM + tgA];
            sB[0][j] = pc[j * C_DIM + tgB];
            sK[0][j] = pc[j * C_DIM];
          }
          #pragma unroll
          for (int k = 0; k < 32; ++k) {
            const int t = 1 + 32 * p + k;
            ASTEP_G(k, t < TbA);
          }
        }
      } else {
        const int ptid = tid - 64;
        const int t0 = 65 + 32 * p;
        if (t0 <= 1023) {
          #pragma unroll
          for (int i = 0; i < 6; ++i) {
            const int task = i * 192 + ptid;
            if (task < 1024) {
              const int row = task >> 5;
              const int c4  = task & 31;
              const int t   = t0 + row;
              if (t <= 1023) {
                const float4 v = *(const float4*)(base + (size_t)t * RSTR + c4 * 4);
                float4 w;
                w.x = __builtin_amdgcn_exp2f(v.x * LOG2E);
                w.y = __builtin_amdgcn_exp2f(v.y * LOG2E);
                w.z = __builtin_amdgcn_exp2f(v.z * LOG2E);
                w.w = __builtin_amdgcn_exp2f(v.w * LOG2E);
                *(float4*)&pf[row * C_DIM + c4 * 4] = w;
                if (t < Tb) {
                  float s = v.x + v.y + v.z + v.w;
                  if (c4 == 0) s -= v.x;
                  klacc += s;
                }
              }
            }
          }
        }
      }
      __syncthreads();
      float* tmp = pc; pc = pn; pn = pf; pf = tmp;
    }

    if (tid < 64) {
      const int l = tid;
      const float Ef = (float)E;
      float* dst = ws + AOFF + b * 257;
      dst[4 * l + 0] = __builtin_amdgcn_logf(r0) + Ef;
      dst[4 * l + 1] = __builtin_amdgcn_logf(r1) + Ef;
      dst[4 * l + 2] = __builtin_amdgcn_logf(r2) + Ef;
      dst[4 * l + 3] = __builtin_amdgcn_logf(r3) + Ef;
      if (l == 63) dst[256] = __builtin_amdgcn_logf(r4) + Ef;
    } else {
      float tot = klacc;
      tot += __shfl_xor(tot, 1, 64);  tot += __shfl_xor(tot, 2, 64);
      tot += __shfl_xor(tot, 4, 64);  tot += __shfl_xor(tot, 8, 64);
      tot += __shfl_xor(tot, 16, 64); tot += __shfl_xor(tot, 32, 64);
      if ((tid & 63) == 0) klred[(tid >> 6) - 1] = tot;
    }
    __syncthreads();
    if (tid == 0) ws[KLA + b] = klred[0] + klred[1] + klred[2];

  } else {
    // ================= BETA half =================
    int tgA = 0, tgB = 0, tgAn = 0, tgBn = 0;
    float skA = 0.f, skB = 0.f, skAn = 0.f, skBn = 0.f;
    float r0 = 0.f, r1 = 0.f, r2 = 0.f, r3 = 0.f, r4 = 0.f;
    int E = SENT;
    float scale = 0.f;
    float sA[2][4], sB[2][4], sK[2][4], sN[2][4];

    if (tid < 64) {
      const int l = tid;
      tgA = targets[b * L_DIM + 2 * l];
      tgB = targets[b * L_DIM + 2 * l + 1];
      const int ni1 = (l < 63) ? (2 * l + 2) : (2 * l);
      const int ni2 = (l < 63) ? (2 * l + 3) : (2 * l + 1);
      tgAn = targets[b * L_DIM + ni1];
      tgBn = targets[b * L_DIM + ni2];
      skA  = (l > 0 && tgA != targets[b * L_DIM + 2 * l - 1]) ? 1.f : 0.f;
      skB  = (tgB != tgA) ? 1.f : 0.f;
      skAn = (l < 63 && tgAn != tgB) ? 1.f : 0.f;
      skBn = (l < 63 && tgBn != tgAn) ? 1.f : 0.f;
      const int Lt = tg_len[b];
      const int s0 = 4 * l;
      r0 = (s0 == 2 * Lt || s0 == 2 * Lt - 1) ? 1.f : 0.f;
      r1 = (s0 + 1 == 2 * Lt || s0 + 1 == 2 * Lt - 1) ? 1.f : 0.f;
      r2 = (s0 + 2 == 2 * Lt || s0 + 2 == 2 * Lt - 1) ? 1.f : 0.f;
      r3 = (s0 + 3 == 2 * Lt || s0 + 3 == 2 * Lt - 1) ? 1.f : 0.f;
      r4 = (s0 + 4 == 2 * Lt || s0 + 4 == 2 * Lt - 1) ? 1.f : 0.f;
      E = (r0 + r1 + r2 + r3 + r4 > 0.f) ? 0 : SENT;
    } else {
      const int ptid = tid - 64;
      #pragma unroll
      for (int i = 0; i < 11; ++i) {
        const int task = i * 192 + ptid;
        if (task < 2048) {
          const int row = task >> 5;
          const int c4  = task & 31;
          const int t   = 2047 - row;
          const float4 v = *(const float4*)(base + (size_t)t * RSTR + c4 * 4);
          float4 w;
          w.x = __builtin_amdgcn_exp2f(v.x * LOG2E);
          w.y = __builtin_amdgcn_exp2f(v.y * LOG2E);
          w.z = __builtin_amdgcn_exp2f(v.z * LOG2E);
          w.w = __builtin_amdgcn_exp2f(v.w * LOG2E);
          *(float4*)&rows[row >> 5][row & 31][c4 * 4] = w;
          if (t < Tb) {
            float s = v.x + v.y + v.z + v.w;
            if (c4 == 0) s -= v.x;
            klacc += s;
          }
        }
      }
    }
    __syncthreads();

    if (tid < 64) { BEXCH(); }
    float* pc = &rows[0][0][0];
    float* pn = &rows[1][0][0];
    float* pf = &rows[2][0][0];

    for (int p = 0; p < NPH; ++p) {
      if (tid < 64) {
        const int rmax = 2047 - 32 * p;
        const int rmin = rmax - 31;
        if (rmax < Tb) {
          #pragma unroll
          for (int j = 0; j < 16; ++j) { BMACRO(j); }
        } else if (rmin < Tb) {
          #pragma unroll
          for (int j = 0; j < 4; ++j) {
            sA[0][j] = pc[j * C_DIM + tgA];
            sB[0][j] = pc[j * C_DIM + tgB];
            sK[0][j] = pc[j * C_DIM];
            sN[0][j] = pc[j * C_DIM + tgAn];
          }
          #pragma unroll
          for (int k = 0; k < 32; ++k) {
            const int r = 2047 - 32 * p - k;
            BSTEP_G(k, r < Tb);
          }
        }
      } else {
        const int ptid = tid - 64;
        const int t0 = 1983 - 32 * p;
        if (t0 >= 1024) {
          #pragma unroll
          for (int i = 0; i < 6; ++i) {
            const int task = i * 192 + ptid;
            if (task < 1024) {
              const int row = task >> 5;
              const int c4  = task & 31;
              const int t   = t0 - row;
              if (t >= 1024) {
                const float4 v = *(const float4*)(base + (size_t)t * RSTR + c4 * 4);
                float4 w;
                w.x = __builtin_amdgcn_exp2f(v.x * LOG2E);
                w.y = __builtin_amdgcn_exp2f(v.y * LOG2E);
                w.z = __builtin_amdgcn_exp2f(v.z * LOG2E);
                w.w = __builtin_amdgcn_exp2f(v.w * LOG2E);
                *(float4*)&pf[row * C_DIM + c4 * 4] = w;
                if (t < Tb) {
                  float s = v.x + v.y + v.z + v.w;
                  if (c4 == 0) s -= v.x;
                  klacc += s;
                }
              }
            }
          }
        }
      }
      __syncthreads();
      float* tmp = pc; pc = pn; pn = pf; pf = tmp;
    }

    if (tid < 64) {
      const int l = tid;
      const float Ef = (float)E;
      float* dst = ws + BOFF + b * 257;
      dst[4 * l + 0] = __builtin_amdgcn_logf(r0) + Ef;
      dst[4 * l + 1] = __builtin_amdgcn_logf(r1) + Ef;
      dst[4 * l + 2] = __builtin_amdgcn_logf(r2) + Ef;
      dst[4 * l + 3] = __builtin_amdgcn_logf(r3) + Ef;
      if (l == 63) dst[256] = __builtin_amdgcn_logf(r4) + Ef;
    } else {
      float tot = klacc;
      tot += __shfl_xor(tot, 1, 64);  tot += __shfl_xor(tot, 2, 64);
      tot += __shfl_xor(tot, 4, 64);  tot += __shfl_xor(tot, 8, 64);
      tot += __shfl_xor(tot, 16, 64); tot += __shfl_xor(tot, 32, 64);
      if ((tid & 63) == 0) klred[(tid >> 6) - 1] = tot;
    }
    __syncthreads();
    if (tid == 0) ws[KLB + b] = klred[0] + klred[1] + klred[2];
  }
}

__global__ __launch_bounds__(64) void ctc_combine_kernel(
    const float* __restrict__ ws_in, const int* __restrict__ in_len,
    float* __restrict__ ws_out)
{
  const int b = blockIdx.x;
  const int l = threadIdx.x;
  const float* a  = ws_in + AOFF + b * 257;
  const float* bb = ws_in + BOFF + b * 257;
  float x0 = a[4 * l + 0] + bb[4 * l + 0];
  float x1 = a[4 * l + 1] + bb[4 * l + 1];
  float x2 = a[4 * l + 2] + bb[4 * l + 2];
  float x3 = a[4 * l + 3] + bb[4 * l + 3];
  float x4 = (l == 63) ? (a[256] + bb[256]) : -3.0e38f;
  float m = fmaxf(fmaxf(fmaxf(x0, x1), fmaxf(x2, x3)), x4);
  m = fmaxf(m, __shfl_xor(m, 1, 64));  m = fmaxf(m, __shfl_xor(m, 2, 64));
  m = fmaxf(m, __shfl_xor(m, 4, 64));  m = fmaxf(m, __shfl_xor(m, 8, 64));
  m = fmaxf(m, __shfl_xor(m, 16, 64)); m = fmaxf(m, __shfl_xor(m, 32, 64));
  const float ms = fmaxf(m, -1.0e37f);
  float s = __builtin_amdgcn_exp2f(x0 - ms) + __builtin_amdgcn_exp2f(x1 - ms)
          + __builtin_amdgcn_exp2f(x2 - ms) + __builtin_amdgcn_exp2f(x3 - ms)
          + __builtin_amdgcn_exp2f(x4 - ms);
  s += __shfl_xor(s, 1, 64);  s += __shfl_xor(s, 2, 64);
  s += __shfl_xor(s, 4, 64);  s += __shfl_xor(s, 8, 64);
  s += __shfl_xor(s, 16, 64); s += __shfl_xor(s, 32, 64);
  if (l == 0) {
    float ctc = 0.f;
    if (s > 0.f && m > -1.0e30f) {
      ctc = -((ms + __builtin_amdgcn_logf(s)) * LN2);
    }
    const int Tb = in_len[b];
    const float u    = 1.0f / (C_DIM - 1);
    const float logu = -4.8441870864585910f;
    const float kls  = ws_in[KLA + b] + ws_in[KLB + b];
    const float klmean = logu - u * kls / (float)Tb;
    ws_out[LOSS + b] = (1.0f - SMOOTH) * ctc + SMOOTH * klmean;
  }
}

__global__ __launch_bounds__(128) void ctc_mean_kernel(
    const float* __restrict__ ws, float* __restrict__ out)
{
  __shared__ float red[128];
  const int tid = threadIdx.x;
  red[tid] = (tid < B_DIM) ? ws[LOSS + tid] : 0.f;
  __syncthreads();
  for (int off = 64; off > 0; off >>= 1) {
    if (tid < off) red[tid] += red[tid + off];
    __syncthreads();
  }
  if (tid == 0) out[0] = red[0] / (float)B_DIM;
}

extern "C" void kernel_launch(void* const* d_in, const int* in_sizes, int n_in,
                              void* d_out, int out_size, void* d_ws, size_t ws_size,
                              hipStream_t stream) {
  const float* lp      = (const float*)d_in[0];
  const int* targets   = (const int*)d_in[1];
  const int* in_len    = (const int*)d_in[2];
  const int* tg_len    = (const int*)d_in[3];
  float* ws  = (float*)d_ws;
  float* out = (float*)d_out;

  hipLaunchKernelGGL(ctc_fused_kernel, dim3(2 * B_DIM), dim3(256), 0, stream,
                     lp, targets, in_len, tg_len, ws);
  hipLaunchKernelGGL(ctc_combine_kernel, dim3(B_DIM), dim3(64), 0, stream,
                     ws, in_len, ws);
  hipLaunchKernelGGL(ctc_mean_kernel, dim3(1), dim3(128), 0, stream,
                     ws, out);
}

// Round 21
// 81.550 us; speedup vs baseline: 1.2309x; 1.2309x over previous
//
#include <hip/hip_runtime.h>
#include <math.h>

#define T_DIM 2048
#define B_DIM 96
#define C_DIM 128
#define L_DIM 128
#define LOG2E 1.4426950408889634f
#define LN2 0.69314718055994531f
#define SMOOTH 0.1f
#define SENT (-(1 << 30))       // virgin lane frame (f32-exact power of 2)
#define SENTF (-1073741824.0f)
#define NPH 32                  // 32 phases x 32 steps per chain

// ws layout (floats)
#define AOFF 0
#define BOFF 24672
#define KLA  49344
#define KLB  49440
#define LOSS 49536

__device__ __forceinline__ float dpp_shr1_f(float x) {
  return __int_as_float(__builtin_amdgcn_update_dpp(
      0, __float_as_int(x), 0x138 /*WAVE_SR1*/, 0xF, 0xF, true));
}
__device__ __forceinline__ float dpp_shl1_f(float x) {
  return __int_as_float(__builtin_amdgcn_update_dpp(
      0, __float_as_int(x), 0x130 /*WAVE_SL1*/, 0xF, 0xF, true));
}

// Window exchange (R18-proven): recenter to 2^50, swap frames, virgin
// pre-adoption, scale = 2^(Es-E) exact pow2.
#define AEXCH() do {                                                         \
  const float m = fmaxf(fmaxf(fmaxf(r0, r1), fmaxf(r2, r3)), r4);            \
  const int sh2 = (m > 0.0f) ? (177 - ((__float_as_int(m) >> 23) & 0xFF)) : 0;\
  r0 = ldexpf(r0, sh2); r1 = ldexpf(r1, sh2); r2 = ldexpf(r2, sh2);          \
  r3 = ldexpf(r3, sh2); r4 = ldexpf(r4, sh2);                                \
  E -= sh2;                                                                  \
  float Esf = dpp_shr1_f((float)E);                                          \
  Esf = (tid == 0) ? SENTF : Esf;                                            \
  const int Es = (int)Esf;                                                   \
  const bool live = (Es != SENT);                                            \
  if (E == SENT && live) E = Es;                                             \
  int sh = (Es - E) - 60; sh = (sh > 0) ? sh : 0; sh = (sh > 252) ? 252 : sh;\
  r0 = ldexpf(r0, -sh); r1 = ldexpf(r1, -sh); r2 = ldexpf(r2, -sh);          \
  r3 = ldexpf(r3, -sh); r4 = ldexpf(r4, -sh);                                \
  E += sh;                                                                   \
  const int diff = Es - E;                                                   \
  int dc = (diff < -126) ? -126 : diff;                                      \
  float sc = __int_as_float((127 + dc) << 23);                               \
  sc = (diff < -126) ? 0.0f : sc;                                            \
  scale = live ? sc : 0.0f;                                                  \
} while (0)

#define BEXCH() do {                                                         \
  const float m = fmaxf(fmaxf(fmaxf(r0, r1), fmaxf(r2, r3)), r4);            \
  const int sh2 = (m > 0.0f) ? (177 - ((__float_as_int(m) >> 23) & 0xFF)) : 0;\
  r0 = ldexpf(r0, sh2); r1 = ldexpf(r1, sh2); r2 = ldexpf(r2, sh2);          \
  r3 = ldexpf(r3, sh2); r4 = ldexpf(r4, sh2);                                \
  E -= sh2;                                                                  \
  float Esf = dpp_shl1_f((float)E);                                          \
  Esf = (tid == 63) ? SENTF : Esf;                                           \
  const int Es = (int)Esf;                                                   \
  const bool live = (Es != SENT);                                            \
  if (E == SENT && live) E = Es;                                             \
  int sh = (Es - E) - 60; sh = (sh > 0) ? sh : 0; sh = (sh > 252) ? 252 : sh;\
  r0 = ldexpf(r0, -sh); r1 = ldexpf(r1, -sh); r2 = ldexpf(r2, -sh);          \
  r3 = ldexpf(r3, -sh); r4 = ldexpf(r4, -sh);                                \
  E += sh;                                                                   \
  const int diff = Es - E;                                                   \
  int dc = (diff < -126) ? -126 : diff;                                      \
  float sc = __int_as_float((127 + dc) << 23);                               \
  sc = (diff < -126) ? 0.0f : sc;                                            \
  scale = live ? sc : 0.0f;                                                  \
} while (0)

// Math-only steps (NO LDS ops) — R18-proven recurrence.
#define AMATH(par_, j_) do {                                                 \
  const float pAv = sA[par_][j_], pBv = sB[par_][j_], pKv = sK[par_][j_];    \
  const float r3s = dpp_shr1_f(r3);                                          \
  const float d3  = r3s * scale;                                             \
  const float n0 = (r0 + d3) * pKv;                                          \
  const float n1 = __builtin_fmaf(skA, d3, r0 + r1) * pAv;                   \
  const float n2 = (r2 + r1) * pKv;                                          \
  const float n3 = __builtin_fmaf(skB, r1, r3 + r2) * pBv;                   \
  const float n4 = (r4 + r3) * pKv;                                          \
  r0 = n0; r1 = n1; r2 = n2; r3 = n3; r4 = n4;                               \
} while (0)

#define BMATH(par_, j_) do {                                                 \
  const float pAv = sA[par_][j_], pBv = sB[par_][j_], pKv = sK[par_][j_];    \
  const float pNv = sN[par_][j_];                                            \
  const float r1s = dpp_shl1_f(r1);                                          \
  const float d5  = r1s * scale;                                             \
  const float g0 = r0 * pKv, g1 = r1 * pAv, g2 = r2 * pKv;                   \
  const float g3 = r3 * pBv, g4 = r4 * pKv, g5 = d5 * pNv;                   \
  const float n0 = g0 + g1;                                                  \
  const float n1 = __builtin_fmaf(skAp, g3, g1 + g2);                        \
  const float n2 = g2 + g3;                                                  \
  const float n3 = __builtin_fmaf(skBp, g5, g3 + g4);                        \
  const float n4 = g4 + g5;                                                  \
  r0 = n0; r1 = n1; r2 = n2; r3 = n3; r4 = n4;                               \
} while (0)

// Batched refill of set (w+1)&1 with rows 4w+4..4w+7 (compile-time).
#define AREFILL(w_) do {                                                     \
  _Pragma("unroll")                                                          \
  for (int j = 0; j < 4; ++j) {                                              \
    const int rr = 4 * (w_) + 4 + j;                                         \
    const float* nr = (rr < 32) ? (pc + rr * C_DIM)                          \
                                : (pn + (rr - 32) * C_DIM);                  \
    sA[((w_) + 1) & 1][j] = nr[tgA];                                         \
    sB[((w_) + 1) & 1][j] = nr[tgB];                                         \
    sK[((w_) + 1) & 1][j] = nr[0];                                           \
  }                                                                          \
} while (0)

#define BREFILL(w_) do {                                                     \
  _Pragma("unroll")                                                          \
  for (int j = 0; j < 4; ++j) {                                              \
    const int rr = 4 * (w_) + 4 + j;                                         \
    const float* nr = (rr < 32) ? (pc + rr * C_DIM)                          \
                                : (pn + (rr - 32) * C_DIM);                  \
    sA[((w_) + 1) & 1][j] = nr[tgA];                                         \
    sB[((w_) + 1) & 1][j] = nr[tgB];                                         \
    sK[((w_) + 1) & 1][j] = nr[0];                                           \
    sN[((w_) + 1) & 1][j] = nr[tgAn];                                        \
  }                                                                          \
} while (0)

// FAST windows: batch loads, then 4 pure-VALU steps, then exchange.
#define AWIN(w_) do {                                                        \
  AREFILL(w_);                                                               \
  AMATH((w_) & 1, 0); AMATH((w_) & 1, 1);                                    \
  AMATH((w_) & 1, 2); AMATH((w_) & 1, 3);                                    \
  AEXCH();                                                                   \
} while (0)

#define BWIN(w_) do {                                                        \
  BREFILL(w_);                                                               \
  BMATH((w_) & 1, 0); BMATH((w_) & 1, 1);                                    \
  BMATH((w_) & 1, 2); BMATH((w_) & 1, 3);                                    \
  BEXCH();                                                                   \
} while (0)

// Guarded single steps for tail phases (refill hoisted outside guard).
#define ASTEP_G(k_, cond_) do {                                              \
  const int kn_ = (k_) + 4;                                                  \
  {                                                                          \
    const float* nr = (kn_ < 32) ? (pc + kn_ * C_DIM)                        \
                                 : (pn + (kn_ - 32) * C_DIM);                \
    sA[(kn_ >> 2) & 1][kn_ & 3] = nr[tgA];                                   \
    sB[(kn_ >> 2) & 1][kn_ & 3] = nr[tgB];                                   \
    sK[(kn_ >> 2) & 1][kn_ & 3] = nr[0];                                     \
  }                                                                          \
  if (cond_) {                                                               \
    AMATH(((k_) >> 2) & 1, (k_) & 3);                                        \
    if (((k_) & 3) == 3) { AEXCH(); }                                        \
  }                                                                          \
} while (0)

#define BSTEP_G(k_, cond_) do {                                              \
  const int kn_ = (k_) + 4;                                                  \
  {                                                                          \
    const float* nr = (kn_ < 32) ? (pc + kn_ * C_DIM)                        \
                                 : (pn + (kn_ - 32) * C_DIM);                \
    sA[(kn_ >> 2) & 1][kn_ & 3] = nr[tgA];                                   \
    sB[(kn_ >> 2) & 1][kn_ & 3] = nr[tgB];                                   \
    sK[(kn_ >> 2) & 1][kn_ & 3] = nr[0];                                     \
    sN[(kn_ >> 2) & 1][kn_ & 3] = nr[tgAn];                                  \
  }                                                                          \
  if (cond_) {                                                               \
    BMATH(((k_) >> 2) & 1, (k_) & 3);                                        \
    if (((k_) & 3) == 3) { BEXCH(); }                                        \
  }                                                                          \
} while (0)

// Blocks 0..95: ALPHA half (t=0..1023). Blocks 96..191: BETA half
// (rows 2047..1024). R18 structure; consumer LDS reads window-batched.
__global__ __launch_bounds__(256) void ctc_fused_kernel(
    const float* __restrict__ lp, const int* __restrict__ targets,
    const int* __restrict__ in_len, const int* __restrict__ tg_len,
    float* __restrict__ ws)
{
  const int tid = threadIdx.x;
  const int bid = blockIdx.x;
  const int isBeta = (bid >= B_DIM);
  const int b = isBeta ? bid - B_DIM : bid;
  const size_t RSTR = (size_t)B_DIM * C_DIM;       // floats per t-row
  const int Tb = in_len[b];
  const float* base = lp + (size_t)b * C_DIM;

  __shared__ float rows[3][32][C_DIM];             // 48 KB ring of PROBS
  __shared__ float klred[3];

  float klacc = 0.f;                               // producers only

  if (!isBeta) {
    // ================= ALPHA half =================
    const int TbA = (Tb < 1024) ? Tb : 1024;
    int tgA = 0, tgB = 0;
    float skA = 0.f, skB = 0.f;
    float r0 = 0.f, r1 = 0.f, r2 = 0.f, r3 = 0.f, r4 = 0.f;
    int E = SENT;
    float scale = 0.f;
    float sA[2][4], sB[2][4], sK[2][4];

    if (tid < 64) {
      const int l = tid;
      tgA = targets[b * L_DIM + 2 * l];
      tgB = targets[b * L_DIM + 2 * l + 1];
      skA = (l > 0 && tgA != targets[b * L_DIM + 2 * l - 1]) ? 1.f : 0.f;
      skB = (tgB != tgA) ? 1.f : 0.f;
      if (l == 0) {
        r0 = __builtin_amdgcn_exp2f(base[0]   * LOG2E);
        r1 = __builtin_amdgcn_exp2f(base[tgA] * LOG2E);
        E = 0;
      }
    } else {
      const int ptid = tid - 64;
      #pragma unroll
      for (int i = 0; i < 11; ++i) {
        const int task = i * 192 + ptid;
        if (task < 2048) {
          const int row = task >> 5;
          const int c4  = task & 31;
          const int t   = 1 + row;
          const float4 v = *(const float4*)(base + (size_t)t * RSTR + c4 * 4);
          float4 w;
          w.x = __builtin_amdgcn_exp2f(v.x * LOG2E);
          w.y = __builtin_amdgcn_exp2f(v.y * LOG2E);
          w.z = __builtin_amdgcn_exp2f(v.z * LOG2E);
          w.w = __builtin_amdgcn_exp2f(v.w * LOG2E);
          *(float4*)&rows[row >> 5][row & 31][c4 * 4] = w;
          if (t < Tb) {
            float s = v.x + v.y + v.z + v.w;
            if (c4 == 0) s -= v.x;
            klacc += s;
          }
        }
      }
      if (ptid < 32 && 0 < Tb) {
        const float4 v = *(const float4*)(base + ptid * 4);
        float s = v.x + v.y + v.z + v.w;
        if (ptid == 0) s -= v.x;
        klacc += s;
      }
    }
    __syncthreads();

    if (tid < 64) {
      #pragma unroll
      for (int j = 0; j < 4; ++j) {
        sA[0][j] = rows[0][j][tgA]; sB[0][j] = rows[0][j][tgB];
        sK[0][j] = rows[0][j][0];
      }
      AEXCH();                                     // initial frame exchange
    }
    float* pc = &rows[0][0][0];
    float* pn = &rows[1][0][0];
    float* pf = &rows[2][0][0];

    for (int p = 0; p < NPH; ++p) {
      if (tid < 64) {
        if (32 * p + 33 <= TbA) {
          #pragma unroll
          for (int w = 0; w < 8; ++w) { AWIN(w); }
        } else {
          #pragma unroll
          for (int k = 0; k < 32; ++k) {
            const int t = 1 + 32 * p + k;
            ASTEP_G(k, t < TbA);
          }
        }
      } else {
        const int ptid = tid - 64;
        const int t0 = 65 + 32 * p;
        if (t0 <= 1023) {
          #pragma unroll
          for (int i = 0; i < 6; ++i) {
            const int task = i * 192 + ptid;
            if (task < 1024) {
              const int row = task >> 5;
              const int c4  = task & 31;
              const int t   = t0 + row;
              if (t <= 1023) {
                const float4 v = *(const float4*)(base + (size_t)t * RSTR + c4 * 4);
                float4 w;
                w.x = __builtin_amdgcn_exp2f(v.x * LOG2E);
                w.y = __builtin_amdgcn_exp2f(v.y * LOG2E);
                w.z = __builtin_amdgcn_exp2f(v.z * LOG2E);
                w.w = __builtin_amdgcn_exp2f(v.w * LOG2E);
                *(float4*)&pf[row * C_DIM + c4 * 4] = w;
                if (t < Tb) {
                  float s = v.x + v.y + v.z + v.w;
                  if (c4 == 0) s -= v.x;
                  klacc += s;
                }
              }
            }
          }
        }
      }
      __syncthreads();
      float* tmp = pc; pc = pn; pn = pf; pf = tmp;
    }

    if (tid < 64) {
      const int l = tid;
      const float Ef = (float)E;
      float* dst = ws + AOFF + b * 257;
      dst[4 * l + 0] = __builtin_amdgcn_logf(r0) + Ef;
      dst[4 * l + 1] = __builtin_amdgcn_logf(r1) + Ef;
      dst[4 * l + 2] = __builtin_amdgcn_logf(r2) + Ef;
      dst[4 * l + 3] = __builtin_amdgcn_logf(r3) + Ef;
      if (l == 63) dst[256] = __builtin_amdgcn_logf(r4) + Ef;
    } else {
      float tot = klacc;
      tot += __shfl_xor(tot, 1, 64);  tot += __shfl_xor(tot, 2, 64);
      tot += __shfl_xor(tot, 4, 64);  tot += __shfl_xor(tot, 8, 64);
      tot += __shfl_xor(tot, 16, 64); tot += __shfl_xor(tot, 32, 64);
      if ((tid & 63) == 0) klred[(tid >> 6) - 1] = tot;
    }
    __syncthreads();
    if (tid == 0) ws[KLA + b] = klred[0] + klred[1] + klred[2];

  } else {
    // ================= BETA half =================
    int tgA = 0, tgB = 0, tgAn = 0;
    float skAp = 0.f, skBp = 0.f;
    float r0 = 0.f, r1 = 0.f, r2 = 0.f, r3 = 0.f, r4 = 0.f;
    int E = SENT;
    float scale = 0.f;
    float sA[2][4], sB[2][4], sK[2][4], sN[2][4];

    if (tid < 64) {
      const int l = tid;
      tgA = targets[b * L_DIM + 2 * l];
      tgB = targets[b * L_DIM + 2 * l + 1];
      const int nidx = (l < 63) ? (2 * l + 2) : (2 * l);
      tgAn = targets[b * L_DIM + nidx];
      skAp = (tgB != tgA) ? 1.f : 0.f;
      skBp = (l < 63 && tgAn != tgB) ? 1.f : 0.f;
      const int Lt = tg_len[b];
      const int s0 = 4 * l;
      r0 = (s0 == 2 * Lt || s0 == 2 * Lt - 1) ? 1.f : 0.f;
      r1 = (s0 + 1 == 2 * Lt || s0 + 1 == 2 * Lt - 1) ? 1.f : 0.f;
      r2 = (s0 + 2 == 2 * Lt || s0 + 2 == 2 * Lt - 1) ? 1.f : 0.f;
      r3 = (s0 + 3 == 2 * Lt || s0 + 3 == 2 * Lt - 1) ? 1.f : 0.f;
      r4 = (s0 + 4 == 2 * Lt || s0 + 4 == 2 * Lt - 1) ? 1.f : 0.f;
      E = (r0 + r1 + r2 + r3 + r4 > 0.f) ? 0 : SENT;
    } else {
      const int ptid = tid - 64;
      #pragma unroll
      for (int i = 0; i < 11; ++i) {
        const int task = i * 192 + ptid;
        if (task < 2048) {
          const int row = task >> 5;                // j = 0..63
          const int c4  = task & 31;
          const int t   = 2047 - row;
          const float4 v = *(const float4*)(base + (size_t)t * RSTR + c4 * 4);
          float4 w;
          w.x = __builtin_amdgcn_exp2f(v.x * LOG2E);
          w.y = __builtin_amdgcn_exp2f(v.y * LOG2E);
          w.z = __builtin_amdgcn_exp2f(v.z * LOG2E);
          w.w = __builtin_amdgcn_exp2f(v.w * LOG2E);
          *(float4*)&rows[row >> 5][row & 31][c4 * 4] = w;
          if (t < Tb) {
            float s = v.x + v.y + v.z + v.w;
            if (c4 == 0) s -= v.x;
            klacc += s;
          }
        }
      }
    }
    __syncthreads();

    if (tid < 64) {
      #pragma unroll
      for (int j = 0; j < 4; ++j) {
        sA[0][j] = rows[0][j][tgA]; sB[0][j] = rows[0][j][tgB];
        sK[0][j] = rows[0][j][0];   sN[0][j] = rows[0][j][tgAn];
      }
      BEXCH();                                     // initial frame exchange
    }
    float* pc = &rows[0][0][0];
    float* pn = &rows[1][0][0];
    float* pf = &rows[2][0][0];

    for (int p = 0; p < NPH; ++p) {
      if (tid < 64) {
        const int rmax = 2047 - 32 * p;
        const int rmin = rmax - 31;
        if (rmax < Tb) {
          #pragma unroll
          for (int w = 0; w < 8; ++w) { BWIN(w); }
        } else if (rmin < Tb) {
          #pragma unroll
          for (int k = 0; k < 32; ++k) {
            const int r = 2047 - 32 * p - k;
            BSTEP_G(k, r < Tb);
          }
        }
      } else {
        const int ptid = tid - 64;
        const int t0 = 1983 - 32 * p;
        if (t0 >= 1024) {
          #pragma unroll
          for (int i = 0; i < 6; ++i) {
            const int task = i * 192 + ptid;
            if (task < 1024) {
              const int row = task >> 5;
              const int c4  = task & 31;
              const int t   = t0 - row;
              if (t >= 1024) {
                const float4 v = *(const float4*)(base + (size_t)t * RSTR + c4 * 4);
                float4 w;
                w.x = __builtin_amdgcn_exp2f(v.x * LOG2E);
                w.y = __builtin_amdgcn_exp2f(v.y * LOG2E);
                w.z = __builtin_amdgcn_exp2f(v.z * LOG2E);
                w.w = __builtin_amdgcn_exp2f(v.w * LOG2E);
                *(float4*)&pf[row * C_DIM + c4 * 4] = w;
                if (t < Tb) {
                  float s = v.x + v.y + v.z + v.w;
                  if (c4 == 0) s -= v.x;
                  klacc += s;
                }
              }
            }
          }
        }
      }
      __syncthreads();
      float* tmp = pc; pc = pn; pn = pf; pf = tmp;
    }

    if (tid < 64) {
      const int l = tid;
      const float Ef = (float)E;
      float* dst = ws + BOFF + b * 257;
      dst[4 * l + 0] = __builtin_amdgcn_logf(r0) + Ef;
      dst[4 * l + 1] = __builtin_amdgcn_logf(r1) + Ef;
      dst[4 * l + 2] = __builtin_amdgcn_logf(r2) + Ef;
      dst[4 * l + 3] = __builtin_amdgcn_logf(r3) + Ef;
      if (l == 63) dst[256] = __builtin_amdgcn_logf(r4) + Ef;
    } else {
      float tot = klacc;
      tot += __shfl_xor(tot, 1, 64);  tot += __shfl_xor(tot, 2, 64);
      tot += __shfl_xor(tot, 4, 64);  tot += __shfl_xor(tot, 8, 64);
      tot += __shfl_xor(tot, 16, 64); tot += __shfl_xor(tot, 32, 64);
      if ((tid & 63) == 0) klred[(tid >> 6) - 1] = tot;
    }
    __syncthreads();
    if (tid == 0) ws[KLB + b] = klred[0] + klred[1] + klred[2];
  }
}

// Per-sample combine: ll = logsumexp_s(alpha_log2[s] + beta_log2[s]); loss.
__global__ __launch_bounds__(64) void ctc_combine_kernel(
    const float* __restrict__ ws_in, const int* __restrict__ in_len,
    float* __restrict__ ws_out)
{
  const int b = blockIdx.x;
  const int l = threadIdx.x;
  const float* a  = ws_in + AOFF + b * 257;
  const float* bb = ws_in + BOFF + b * 257;
  float x0 = a[4 * l + 0] + bb[4 * l + 0];
  float x1 = a[4 * l + 1] + bb[4 * l + 1];
  float x2 = a[4 * l + 2] + bb[4 * l + 2];
  float x3 = a[4 * l + 3] + bb[4 * l + 3];
  float x4 = (l == 63) ? (a[256] + bb[256]) : -3.0e38f;
  float m = fmaxf(fmaxf(fmaxf(x0, x1), fmaxf(x2, x3)), x4);
  m = fmaxf(m, __shfl_xor(m, 1, 64));  m = fmaxf(m, __shfl_xor(m, 2, 64));
  m = fmaxf(m, __shfl_xor(m, 4, 64));  m = fmaxf(m, __shfl_xor(m, 8, 64));
  m = fmaxf(m, __shfl_xor(m, 16, 64)); m = fmaxf(m, __shfl_xor(m, 32, 64));
  const float ms = fmaxf(m, -1.0e37f);
  float s = __builtin_amdgcn_exp2f(x0 - ms) + __builtin_amdgcn_exp2f(x1 - ms)
          + __builtin_amdgcn_exp2f(x2 - ms) + __builtin_amdgcn_exp2f(x3 - ms)
          + __builtin_amdgcn_exp2f(x4 - ms);
  s += __shfl_xor(s, 1, 64);  s += __shfl_xor(s, 2, 64);
  s += __shfl_xor(s, 4, 64);  s += __shfl_xor(s, 8, 64);
  s += __shfl_xor(s, 16, 64); s += __shfl_xor(s, 32, 64);
  if (l == 0) {
    float ctc = 0.f;
    if (s > 0.f && m > -1.0e30f) {
      ctc = -((ms + __builtin_amdgcn_logf(s)) * LN2);
    }
    const int Tb = in_len[b];
    const float u    = 1.0f / (C_DIM - 1);
    const float logu = -4.8441870864585910f;       // log(1/127)
    const float kls  = ws_in[KLA + b] + ws_in[KLB + b];
    const float klmean = logu - u * kls / (float)Tb;
    ws_out[LOSS + b] = (1.0f - SMOOTH) * ctc + SMOOTH * klmean;
  }
}

__global__ __launch_bounds__(128) void ctc_mean_kernel(
    const float* __restrict__ ws, float* __restrict__ out)
{
  __shared__ float red[128];
  const int tid = threadIdx.x;
  red[tid] = (tid < B_DIM) ? ws[LOSS + tid] : 0.f;
  __syncthreads();
  for (int off = 64; off > 0; off >>= 1) {
    if (tid < off) red[tid] += red[tid + off];
    __syncthreads();
  }
  if (tid == 0) out[0] = red[0] / (float)B_DIM;
}

extern "C" void kernel_launch(void* const* d_in, const int* in_sizes, int n_in,
                              void* d_out, int out_size, void* d_ws, size_t ws_size,
                              hipStream_t stream) {
  const float* lp      = (const float*)d_in[0];
  const int* targets   = (const int*)d_in[1];
  const int* in_len    = (const int*)d_in[2];
  const int* tg_len    = (const int*)d_in[3];
  float* ws  = (float*)d_ws;
  float* out = (float*)d_out;

  hipLaunchKernelGGL(ctc_fused_kernel, dim3(2 * B_DIM), dim3(256), 0, stream,
                     lp, targets, in_len, tg_len, ws);
  hipLaunchKernelGGL(ctc_combine_kernel, dim3(B_DIM), dim3(64), 0, stream,
                     ws, in_len, ws);
  hipLaunchKernelGGL(ctc_mean_kernel, dim3(1), dim3(128), 0, stream,
                     ws, out);
}